// Round 4
// baseline (193.538 us; speedup 1.0000x reference)
//
#include <hip/hip_runtime.h>
#include <hip/hip_bf16.h>

// PrototypicalNetwork: out[q,c] = -1/8 * sum_b sqrt(max(q2[q] + p2[b,c] - 2*qp[b,q,c], 0))
// bf16 MFMA 16x16x32 for qp GEMM (M=65536, N=1024, K=128).
// R10 = R9 (32-row blocks, 3 waves/EU, p2 scalar in-loop, q2 pre-scaled)
//  + 2-deep prefetch: 3-buffer rotation, loads issued 2 steps ahead of use,
//    16-step loop FULLY unrolled so buf[(s+2)%3]/pp[..] are compile-time
//    (rule #20: no runtime-indexed reg arrays). Targets the residual latency
//    exposure (R8 profile: all pipes <30% busy): 1-deep ping-pong gave the
//    C-init only ~1 step (~170 cyc issue) to cover ~200-400 cyc L2 latency.
// Est live ~145 regs <= 168 cap -> keeps 3 waves/EU.

#define DIM   128
#define NCLS  128
#define SHOTS 32
#define NB    8
#define NQ    65536

using short8 = __attribute__((ext_vector_type(8))) short;
using f32x4  = __attribute__((ext_vector_type(4))) float;

__device__ __forceinline__ unsigned short f2bf(float x) {
  union { float f; unsigned u; } v; v.f = x;
  unsigned r = v.u + 0x7fffu + ((v.u >> 16) & 1u);   // RNE
  return (unsigned short)(r >> 16);
}

__device__ __forceinline__ short8 pack8_bf16(float4 a, float4 b) {
  // v_cvt_pk_bf16_f32 on gfx950 (RNE), 4 insts for 8 elements
  __hip_bfloat162 p0 = __float22bfloat162_rn(make_float2(a.x, a.y));
  __hip_bfloat162 p1 = __float22bfloat162_rn(make_float2(a.z, a.w));
  __hip_bfloat162 p2 = __float22bfloat162_rn(make_float2(b.x, b.y));
  __hip_bfloat162 p3 = __float22bfloat162_rn(make_float2(b.z, b.w));
  union { __hip_bfloat162 h[4]; short8 s; } u;
  u.h[0] = p0; u.h[1] = p1; u.h[2] = p2; u.h[3] = p3;
  return u.s;
}

__device__ __forceinline__ float fast_sqrt(float x) {
#if __has_builtin(__builtin_amdgcn_sqrtf)
  return __builtin_amdgcn_sqrtf(x);   // raw v_sqrt_f32 (never IEEE sqrtf here — R3 regression)
#else
  return sqrtf(x);
#endif
}

// ---------------------------------------------------------------------------
// Kernel 1: bootstrap-mean protos -> bf16(-proto/32) in MFMA B-frag-major
// layout, plus p2[b,c] = |proto|^2 / 64 (fp32).
// B-frag layout (16x16x32): lane holds B[n=lane&15][k=(lane>>4)*8+j].
// Slot = (b*8+ct)*4+kiter; one slot = 64 lanes * 16 B = 1 KB contiguous.
// ---------------------------------------------------------------------------
__global__ __launch_bounds__(128) void proto_kernel(
    const float* __restrict__ sup, const int* __restrict__ bidx,
    unsigned short* __restrict__ pfrag, float* __restrict__ p2) {
  int bc = blockIdx.x;            // b*128 + c
  int c  = bc & (NCLS - 1);
  int d  = threadIdx.x;           // 0..127 = feature dim
  __shared__ int   sidx[SHOTS];
  __shared__ float wsum[2];
  if (d < SHOTS) sidx[d] = bidx[bc * SHOTS + d];
  __syncthreads();
  float acc = 0.f;
  const float* base = sup + c * SHOTS * DIM + d;
  #pragma unroll
  for (int s = 0; s < SHOTS; ++s) acc += base[sidx[s] * DIM];
  float proto = acc * (1.0f / 32.0f);

  int b     = bc >> 7;
  int ct    = c >> 4, l15c = c & 15;
  int kiter = d >> 5, quad = (d >> 3) & 3, j = d & 7;
  int lane  = l15c + (quad << 4);
  int slot  = (b * 8 + ct) * 4 + kiter;
  pfrag[slot * 512 + lane * 8 + j] = f2bf(proto * -0.03125f);  // -proto/32

  float sq = proto * proto;
  #pragma unroll
  for (int off = 32; off > 0; off >>= 1) sq += __shfl_down(sq, off, 64);
  if ((d & 63) == 0) wsum[d >> 6] = sq;
  __syncthreads();
  if (d == 0) p2[bc] = (wsum[0] + wsum[1]) * (1.0f / 64.0f);
}

// ---------------------------------------------------------------------------
// Kernel 2: block = 32 query rows x 128 classes, 4 waves, grid 2048.
// Stage: wave w converts rows [8w, 8w+8) to A-frag layout in LDS. Every wave
// then reads all 8 A-frags (2mt x 4k) and runs a 16-step (b, jj) loop over
// its two c-tiles with a 3-buffer, 2-deep prefetch. One barrier total.
// ---------------------------------------------------------------------------
#define SLOT_STRIDE 520   // 512 shorts payload + 8 pad -> slot base moves 4 banks

__global__ __launch_bounds__(256, 3) void dist_kernel(
    const float* __restrict__ q, const uint4* __restrict__ pfrag,
    const float* __restrict__ p2, float* __restrict__ out) {
  int tid  = threadIdx.x;
  int w    = tid >> 6, lane = tid & 63;
  int l15  = lane & 15, quad = lane >> 4;
  int q0   = blockIdx.x << 5;                        // 32 rows per block

  __shared__ unsigned short aflds[8 * SLOT_STRIDE];  // A-frags, slot = mt*4 + i
  __shared__ float q2s[32];                          // |q|^2/64 per row

  // --- staging: this wave converts rows 8w..8w+7; lane = (row_local, chunk) ---
  // chunk = 16-float slice of D. A-frag target: slot (mt, i=chunk>>1), within
  // slot position p = quad*16 + m, 8 shorts each; this lane covers quads
  // (chunk&1)*2 and (chunk&1)*2+1 of row m.
  {
    int rloc  = w * 8 + (lane >> 3);        // 0..31 local row
    int chunk = lane & 7;
    const float* src = q + (size_t)(q0 + rloc) * DIM + chunk * 16;
    float4 x0 = *reinterpret_cast<const float4*>(src);
    float4 x1 = *reinterpret_cast<const float4*>(src + 4);
    float4 x2 = *reinterpret_cast<const float4*>(src + 8);
    float4 x3 = *reinterpret_cast<const float4*>(src + 12);
    float s = x0.x*x0.x + x0.y*x0.y + x0.z*x0.z + x0.w*x0.w
            + x1.x*x1.x + x1.y*x1.y + x1.z*x1.z + x1.w*x1.w
            + x2.x*x2.x + x2.y*x2.y + x2.z*x2.z + x2.w*x2.w
            + x3.x*x3.x + x3.y*x3.y + x3.z*x3.z + x3.w*x3.w;
    s += __shfl_down(s, 4, 8);              // reduce over the row's 8 chunks
    s += __shfl_down(s, 2, 8);
    s += __shfl_down(s, 1, 8);
    if (chunk == 0) q2s[rloc] = s * (1.0f / 64.0f);  // pre-scaled q2'

    int mt = rloc >> 4, m = rloc & 15, i = chunk >> 1, h = chunk & 1;
    unsigned short* base = &aflds[(mt * 4 + i) * SLOT_STRIDE];
    *reinterpret_cast<short8*>(&base[((h * 2 + 0) * 16 + m) * 8]) = pack8_bf16(x0, x1);
    *reinterpret_cast<short8*>(&base[((h * 2 + 1) * 16 + m) * 8]) = pack8_bf16(x2, x3);
  }
  __syncthreads();

  // --- every wave pulls all 8 A-frags + its q2' rows from LDS ---
  short8 af[2][4];
  #pragma unroll
  for (int mt = 0; mt < 2; ++mt)
    #pragma unroll
    for (int k = 0; k < 4; ++k)
      af[mt][k] = *reinterpret_cast<const short8*>(
          &aflds[(mt * 4 + k) * SLOT_STRIDE + lane * 8]);

  f32x4 q2r[2];                    // q2' for C/D rows quad*4..+3 of each m-tile
  #pragma unroll
  for (int mt = 0; mt < 2; ++mt)
    q2r[mt] = *reinterpret_cast<const f32x4*>(&q2s[mt * 16 + quad * 4]);

  f32x4 oaccA[2], oaccB[2];        // jj=0 / jj=1 accumulators (static index)
  #pragma unroll
  for (int mt = 0; mt < 2; ++mt) {
    oaccA[mt] = (f32x4){0.f, 0.f, 0.f, 0.f};
    oaccB[mt] = (f32x4){0.f, 0.f, 0.f, 0.f};
  }

  // --- 16-step (b, jj) loop, 3-buffer rotation, 2-deep prefetch ---
  // step S: b = S>>1, jj = S&1 (X c-tile = w*2, Y = w*2+1).
  // Fully unrolled: all SL indices are compile-time constants.
  uint4 buf[3][4];
  float pp[3];

  #define LOAD_S(SL, S)                                                       \
    {                                                                         \
      int b_ = (S) >> 1, jj_ = (S) & 1;                                       \
      const uint4* bp = pfrag + (size_t)((b_ * 8 + w * 2 + jj_) * 4) * 64 + lane; \
      _Pragma("unroll")                                                       \
      for (int k = 0; k < 4; ++k) buf[SL][k] = bp[k * 64];                    \
      pp[SL] = p2[b_ * NCLS + (w * 2 + jj_) * 16 + l15];                      \
    }

  #define COMPUTE_S(SL, OA)                                                   \
    {                                                                         \
      f32x4 qp[2];                                                            \
      _Pragma("unroll")                                                       \
      for (int mt = 0; mt < 2; ++mt)                                          \
        _Pragma("unroll")                                                     \
        for (int r = 0; r < 4; ++r)                                           \
          qp[mt][r] = q2r[mt][r] + pp[SL];                                    \
      _Pragma("unroll")                                                       \
      for (int k = 0; k < 4; ++k) {                                           \
        short8 bfk = __builtin_bit_cast(short8, buf[SL][k]);                  \
        _Pragma("unroll")                                                     \
        for (int mt = 0; mt < 2; ++mt)                                        \
          qp[mt] = __builtin_amdgcn_mfma_f32_16x16x32_bf16(af[mt][k], bfk, qp[mt], 0, 0, 0); \
      }                                                                       \
      _Pragma("unroll")                                                       \
      for (int mt = 0; mt < 2; ++mt)                                          \
        _Pragma("unroll")                                                     \
        for (int r = 0; r < 4; ++r)                                           \
          OA[mt][r] += fast_sqrt(fmaxf(qp[mt][r], 0.0f));                     \
    }

  LOAD_S(0, 0)
  LOAD_S(1, 1)
  #pragma unroll
  for (int s = 0; s < 16; ++s) {
    if (s + 2 < 16) { LOAD_S((s + 2) % 3, s + 2) }   // 2 steps ahead
    if ((s & 1) == 0) { COMPUTE_S(s % 3, oaccA) }
    else              { COMPUTE_S(s % 3, oaccB) }
  }
  #undef LOAD_S
  #undef COMPUTE_S

  // --- store: row = q0 + mt2*16 + quad*4 + r, col = (2w+jj)*16 + l15 ---
  int colA = (w * 2 + 0) * 16 + l15;
  int colB = (w * 2 + 1) * 16 + l15;
  #pragma unroll
  for (int mt2 = 0; mt2 < 2; ++mt2) {
    #pragma unroll
    for (int r = 0; r < 4; ++r) {
      int row = q0 + mt2 * 16 + quad * 4 + r;
      out[(size_t)row * NCLS + colA] = -oaccA[mt2][r];
      out[(size_t)row * NCLS + colB] = -oaccB[mt2][r];
    }
  }
}

extern "C" void kernel_launch(void* const* d_in, const int* in_sizes, int n_in,
                              void* d_out, int out_size, void* d_ws, size_t ws_size,
                              hipStream_t stream) {
  const float* sup   = (const float*)d_in[0];   // [4096,128] f32
  // d_in[1] = support_labels (unused: sorted/balanced by construction)
  const float* query = (const float*)d_in[2];   // [65536,128] f32
  const int*   bidx  = (const int*)d_in[3];     // [8,128,32] i32
  float* out = (float*)d_out;                   // [65536,128] f32

  unsigned short* pfrag = (unsigned short*)d_ws;              // 256 KB bf16 frags
  float* p2 = (float*)((char*)d_ws + (size_t)NB * NCLS * DIM * 2); // 4 KB

  proto_kernel<<<NB * NCLS, 128, 0, stream>>>(sup, bidx, pfrag, p2);
  dist_kernel<<<NQ / 32, 256, 0, stream>>>(query, (const uint4*)pfrag, p2, out);
}

// Round 5
// 129.100 us; speedup vs baseline: 1.4991x; 1.4991x over previous
//
#include <hip/hip_runtime.h>
#include <hip/hip_bf16.h>

// PrototypicalNetwork: out[q,c] = -1/8 * sum_b sqrt(max(q2[q] + p2[b,c] - 2*qp[b,q,c], 0))
// bf16 MFMA 16x16x32 for qp GEMM (M=65536, N=1024, K=128).
// R11 = R10's 2-deep prefetch, unspilled. R8/R10 post-mortem: with AGPRs live,
// __launch_bounds__(256,3)'s ~170-reg unified budget splits 84 arch + 84 acc
// (rocprof showed VGPR_Count=84 both times) -> af/buf spilled to scratch
// (R10: 300 MB scratch traffic, dist 121us). (256,2) gives ~128 arch + 128 acc;
// arch live ~115 (af 32 + 3x4 uint4 bufs 48 + q2r 8 + addressing) fits.
// Single-variable change vs R10: launch bounds only. Tests prefetch depth at
// the 2 waves/EU occupancy R7 already validated (110.8us, 1-deep).

#define DIM   128
#define NCLS  128
#define SHOTS 32
#define NB    8
#define NQ    65536

using short8 = __attribute__((ext_vector_type(8))) short;
using f32x4  = __attribute__((ext_vector_type(4))) float;

__device__ __forceinline__ unsigned short f2bf(float x) {
  union { float f; unsigned u; } v; v.f = x;
  unsigned r = v.u + 0x7fffu + ((v.u >> 16) & 1u);   // RNE
  return (unsigned short)(r >> 16);
}

__device__ __forceinline__ short8 pack8_bf16(float4 a, float4 b) {
  // v_cvt_pk_bf16_f32 on gfx950 (RNE), 4 insts for 8 elements
  __hip_bfloat162 p0 = __float22bfloat162_rn(make_float2(a.x, a.y));
  __hip_bfloat162 p1 = __float22bfloat162_rn(make_float2(a.z, a.w));
  __hip_bfloat162 p2 = __float22bfloat162_rn(make_float2(b.x, b.y));
  __hip_bfloat162 p3 = __float22bfloat162_rn(make_float2(b.z, b.w));
  union { __hip_bfloat162 h[4]; short8 s; } u;
  u.h[0] = p0; u.h[1] = p1; u.h[2] = p2; u.h[3] = p3;
  return u.s;
}

__device__ __forceinline__ float fast_sqrt(float x) {
#if __has_builtin(__builtin_amdgcn_sqrtf)
  return __builtin_amdgcn_sqrtf(x);   // raw v_sqrt_f32 (never IEEE sqrtf here — R3 regression)
#else
  return sqrtf(x);
#endif
}

// ---------------------------------------------------------------------------
// Kernel 1: bootstrap-mean protos -> bf16(-proto/32) in MFMA B-frag-major
// layout, plus p2[b,c] = |proto|^2 / 64 (fp32).
// B-frag layout (16x16x32): lane holds B[n=lane&15][k=(lane>>4)*8+j].
// Slot = (b*8+ct)*4+kiter; one slot = 64 lanes * 16 B = 1 KB contiguous.
// ---------------------------------------------------------------------------
__global__ __launch_bounds__(128) void proto_kernel(
    const float* __restrict__ sup, const int* __restrict__ bidx,
    unsigned short* __restrict__ pfrag, float* __restrict__ p2) {
  int bc = blockIdx.x;            // b*128 + c
  int c  = bc & (NCLS - 1);
  int d  = threadIdx.x;           // 0..127 = feature dim
  __shared__ int   sidx[SHOTS];
  __shared__ float wsum[2];
  if (d < SHOTS) sidx[d] = bidx[bc * SHOTS + d];
  __syncthreads();
  float acc = 0.f;
  const float* base = sup + c * SHOTS * DIM + d;
  #pragma unroll
  for (int s = 0; s < SHOTS; ++s) acc += base[sidx[s] * DIM];
  float proto = acc * (1.0f / 32.0f);

  int b     = bc >> 7;
  int ct    = c >> 4, l15c = c & 15;
  int kiter = d >> 5, quad = (d >> 3) & 3, j = d & 7;
  int lane  = l15c + (quad << 4);
  int slot  = (b * 8 + ct) * 4 + kiter;
  pfrag[slot * 512 + lane * 8 + j] = f2bf(proto * -0.03125f);  // -proto/32

  float sq = proto * proto;
  #pragma unroll
  for (int off = 32; off > 0; off >>= 1) sq += __shfl_down(sq, off, 64);
  if ((d & 63) == 0) wsum[d >> 6] = sq;
  __syncthreads();
  if (d == 0) p2[bc] = (wsum[0] + wsum[1]) * (1.0f / 64.0f);
}

// ---------------------------------------------------------------------------
// Kernel 2: block = 32 query rows x 128 classes, 4 waves, grid 2048.
// Stage: wave w converts rows [8w, 8w+8) to A-frag layout in LDS. Every wave
// then reads all 8 A-frags (2mt x 4k) and runs a 16-step (b, jj) loop over
// its two c-tiles with a 3-buffer, 2-deep prefetch. One barrier total.
// ---------------------------------------------------------------------------
#define SLOT_STRIDE 520   // 512 shorts payload + 8 pad -> slot base moves 4 banks

__global__ __launch_bounds__(256, 2) void dist_kernel(
    const float* __restrict__ q, const uint4* __restrict__ pfrag,
    const float* __restrict__ p2, float* __restrict__ out) {
  int tid  = threadIdx.x;
  int w    = tid >> 6, lane = tid & 63;
  int l15  = lane & 15, quad = lane >> 4;
  int q0   = blockIdx.x << 5;                        // 32 rows per block

  __shared__ unsigned short aflds[8 * SLOT_STRIDE];  // A-frags, slot = mt*4 + i
  __shared__ float q2s[32];                          // |q|^2/64 per row

  // --- staging: this wave converts rows 8w..8w+7; lane = (row_local, chunk) ---
  // chunk = 16-float slice of D. A-frag target: slot (mt, i=chunk>>1), within
  // slot position p = quad*16 + m, 8 shorts each; this lane covers quads
  // (chunk&1)*2 and (chunk&1)*2+1 of row m.
  {
    int rloc  = w * 8 + (lane >> 3);        // 0..31 local row
    int chunk = lane & 7;
    const float* src = q + (size_t)(q0 + rloc) * DIM + chunk * 16;
    float4 x0 = *reinterpret_cast<const float4*>(src);
    float4 x1 = *reinterpret_cast<const float4*>(src + 4);
    float4 x2 = *reinterpret_cast<const float4*>(src + 8);
    float4 x3 = *reinterpret_cast<const float4*>(src + 12);
    float s = x0.x*x0.x + x0.y*x0.y + x0.z*x0.z + x0.w*x0.w
            + x1.x*x1.x + x1.y*x1.y + x1.z*x1.z + x1.w*x1.w
            + x2.x*x2.x + x2.y*x2.y + x2.z*x2.z + x2.w*x2.w
            + x3.x*x3.x + x3.y*x3.y + x3.z*x3.z + x3.w*x3.w;
    s += __shfl_down(s, 4, 8);              // reduce over the row's 8 chunks
    s += __shfl_down(s, 2, 8);
    s += __shfl_down(s, 1, 8);
    if (chunk == 0) q2s[rloc] = s * (1.0f / 64.0f);  // pre-scaled q2'

    int mt = rloc >> 4, m = rloc & 15, i = chunk >> 1, h = chunk & 1;
    unsigned short* base = &aflds[(mt * 4 + i) * SLOT_STRIDE];
    *reinterpret_cast<short8*>(&base[((h * 2 + 0) * 16 + m) * 8]) = pack8_bf16(x0, x1);
    *reinterpret_cast<short8*>(&base[((h * 2 + 1) * 16 + m) * 8]) = pack8_bf16(x2, x3);
  }
  __syncthreads();

  // --- every wave pulls all 8 A-frags + its q2' rows from LDS ---
  short8 af[2][4];
  #pragma unroll
  for (int mt = 0; mt < 2; ++mt)
    #pragma unroll
    for (int k = 0; k < 4; ++k)
      af[mt][k] = *reinterpret_cast<const short8*>(
          &aflds[(mt * 4 + k) * SLOT_STRIDE + lane * 8]);

  f32x4 q2r[2];                    // q2' for C/D rows quad*4..+3 of each m-tile
  #pragma unroll
  for (int mt = 0; mt < 2; ++mt)
    q2r[mt] = *reinterpret_cast<const f32x4*>(&q2s[mt * 16 + quad * 4]);

  f32x4 oaccA[2], oaccB[2];        // jj=0 / jj=1 accumulators (static index)
  #pragma unroll
  for (int mt = 0; mt < 2; ++mt) {
    oaccA[mt] = (f32x4){0.f, 0.f, 0.f, 0.f};
    oaccB[mt] = (f32x4){0.f, 0.f, 0.f, 0.f};
  }

  // --- 16-step (b, jj) loop, 3-buffer rotation, 2-deep prefetch ---
  // step S: b = S>>1, jj = S&1 (X c-tile = w*2, Y = w*2+1).
  // Fully unrolled: all SL indices are compile-time constants.
  uint4 buf[3][4];
  float pp[3];

  #define LOAD_S(SL, S)                                                       \
    {                                                                         \
      int b_ = (S) >> 1, jj_ = (S) & 1;                                       \
      const uint4* bp = pfrag + (size_t)((b_ * 8 + w * 2 + jj_) * 4) * 64 + lane; \
      _Pragma("unroll")                                                       \
      for (int k = 0; k < 4; ++k) buf[SL][k] = bp[k * 64];                    \
      pp[SL] = p2[b_ * NCLS + (w * 2 + jj_) * 16 + l15];                      \
    }

  #define COMPUTE_S(SL, OA)                                                   \
    {                                                                         \
      f32x4 qp[2];                                                            \
      _Pragma("unroll")                                                       \
      for (int mt = 0; mt < 2; ++mt)                                          \
        _Pragma("unroll")                                                     \
        for (int r = 0; r < 4; ++r)                                           \
          qp[mt][r] = q2r[mt][r] + pp[SL];                                    \
      _Pragma("unroll")                                                       \
      for (int k = 0; k < 4; ++k) {                                           \
        short8 bfk = __builtin_bit_cast(short8, buf[SL][k]);                  \
        _Pragma("unroll")                                                     \
        for (int mt = 0; mt < 2; ++mt)                                        \
          qp[mt] = __builtin_amdgcn_mfma_f32_16x16x32_bf16(af[mt][k], bfk, qp[mt], 0, 0, 0); \
      }                                                                       \
      _Pragma("unroll")                                                       \
      for (int mt = 0; mt < 2; ++mt)                                          \
        _Pragma("unroll")                                                     \
        for (int r = 0; r < 4; ++r)                                           \
          OA[mt][r] += fast_sqrt(fmaxf(qp[mt][r], 0.0f));                     \
    }

  LOAD_S(0, 0)
  LOAD_S(1, 1)
  #pragma unroll
  for (int s = 0; s < 16; ++s) {
    if (s + 2 < 16) { LOAD_S((s + 2) % 3, s + 2) }   // 2 steps ahead
    if ((s & 1) == 0) { COMPUTE_S(s % 3, oaccA) }
    else              { COMPUTE_S(s % 3, oaccB) }
  }
  #undef LOAD_S
  #undef COMPUTE_S

  // --- store: row = q0 + mt2*16 + quad*4 + r, col = (2w+jj)*16 + l15 ---
  int colA = (w * 2 + 0) * 16 + l15;
  int colB = (w * 2 + 1) * 16 + l15;
  #pragma unroll
  for (int mt2 = 0; mt2 < 2; ++mt2) {
    #pragma unroll
    for (int r = 0; r < 4; ++r) {
      int row = q0 + mt2 * 16 + quad * 4 + r;
      out[(size_t)row * NCLS + colA] = -oaccA[mt2][r];
      out[(size_t)row * NCLS + colB] = -oaccB[mt2][r];
    }
  }
}

extern "C" void kernel_launch(void* const* d_in, const int* in_sizes, int n_in,
                              void* d_out, int out_size, void* d_ws, size_t ws_size,
                              hipStream_t stream) {
  const float* sup   = (const float*)d_in[0];   // [4096,128] f32
  // d_in[1] = support_labels (unused: sorted/balanced by construction)
  const float* query = (const float*)d_in[2];   // [65536,128] f32
  const int*   bidx  = (const int*)d_in[3];     // [8,128,32] i32
  float* out = (float*)d_out;                   // [65536,128] f32

  unsigned short* pfrag = (unsigned short*)d_ws;              // 256 KB bf16 frags
  float* p2 = (float*)((char*)d_ws + (size_t)NB * NCLS * DIM * 2); // 4 KB

  proto_kernel<<<NB * NCLS, 128, 0, stream>>>(sup, bidx, pfrag, p2);
  dist_kernel<<<NQ / 32, 256, 0, stream>>>(query, (const uint4*)pfrag, p2, out);
}

// Round 6
// 109.854 us; speedup vs baseline: 1.7618x; 1.1752x over previous
//
#include <hip/hip_runtime.h>
#include <hip/hip_bf16.h>

// PrototypicalNetwork: out[q,c] = -1/8 * sum_b sqrt(max(q2[q] + p2[b,c] - 2*qp[b,q,c], 0))
// bf16 MFMA 16x16x32 for qp GEMM (M=65536, N=1024, K=128).
// R12 = R7 verbatim (the measured-best 110.8us config: 64-row blocks, LDS
// A-frag staging, packed bf16 cvt, 1-deep (b)-ping-pong, algebra in MFMA
// C-init, 2 waves/EU) + s_setprio(1) around each MFMA cluster (T5).
// Rationale: R8-R11 isolated and nulled occupancy (3w/EU), prefetch depth
// (2-deep: -18us), and further L2 reuse. R7's b-loop waves are free-running
// (one barrier total) -> the independent-wave regime where setprio measured
// +4-7% (m191); cost is 2 SALU/step and zero registers.

#define DIM   128
#define NCLS  128
#define SHOTS 32
#define NB    8
#define NQ    65536

using short8 = __attribute__((ext_vector_type(8))) short;
using f32x4  = __attribute__((ext_vector_type(4))) float;

__device__ __forceinline__ unsigned short f2bf(float x) {
  union { float f; unsigned u; } v; v.f = x;
  unsigned r = v.u + 0x7fffu + ((v.u >> 16) & 1u);   // RNE
  return (unsigned short)(r >> 16);
}

__device__ __forceinline__ short8 pack8_bf16(float4 a, float4 b) {
  // v_cvt_pk_bf16_f32 on gfx950 (RNE), 4 insts for 8 elements
  __hip_bfloat162 p0 = __float22bfloat162_rn(make_float2(a.x, a.y));
  __hip_bfloat162 p1 = __float22bfloat162_rn(make_float2(a.z, a.w));
  __hip_bfloat162 p2 = __float22bfloat162_rn(make_float2(b.x, b.y));
  __hip_bfloat162 p3 = __float22bfloat162_rn(make_float2(b.z, b.w));
  union { __hip_bfloat162 h[4]; short8 s; } u;
  u.h[0] = p0; u.h[1] = p1; u.h[2] = p2; u.h[3] = p3;
  return u.s;
}

__device__ __forceinline__ float fast_sqrt(float x) {
#if __has_builtin(__builtin_amdgcn_sqrtf)
  return __builtin_amdgcn_sqrtf(x);   // raw v_sqrt_f32 (never IEEE sqrtf here — R3 regression)
#else
  return sqrtf(x);
#endif
}

// ---------------------------------------------------------------------------
// Kernel 1: bootstrap-mean protos -> bf16(-proto/32) in MFMA B-frag-major
// layout, plus p2[b,c] = |proto|^2 / 64 (fp32).
// B-frag layout (16x16x32): lane holds B[n=lane&15][k=(lane>>4)*8+j].
// Slot = (b*8+ct)*4+kiter; one slot = 64 lanes * 16 B = 1 KB contiguous.
// ---------------------------------------------------------------------------
__global__ __launch_bounds__(128) void proto_kernel(
    const float* __restrict__ sup, const int* __restrict__ bidx,
    unsigned short* __restrict__ pfrag, float* __restrict__ p2) {
  int bc = blockIdx.x;            // b*128 + c
  int c  = bc & (NCLS - 1);
  int d  = threadIdx.x;           // 0..127 = feature dim
  __shared__ int   sidx[SHOTS];
  __shared__ float wsum[2];
  if (d < SHOTS) sidx[d] = bidx[bc * SHOTS + d];
  __syncthreads();
  float acc = 0.f;
  const float* base = sup + c * SHOTS * DIM + d;
  #pragma unroll
  for (int s = 0; s < SHOTS; ++s) acc += base[sidx[s] * DIM];
  float proto = acc * (1.0f / 32.0f);

  int b     = bc >> 7;
  int ct    = c >> 4, l15c = c & 15;
  int kiter = d >> 5, quad = (d >> 3) & 3, j = d & 7;
  int lane  = l15c + (quad << 4);
  int slot  = (b * 8 + ct) * 4 + kiter;
  pfrag[slot * 512 + lane * 8 + j] = f2bf(proto * -0.03125f);  // -proto/32

  float sq = proto * proto;
  #pragma unroll
  for (int off = 32; off > 0; off >>= 1) sq += __shfl_down(sq, off, 64);
  if ((d & 63) == 0) wsum[d >> 6] = sq;
  __syncthreads();
  if (d == 0) p2[bc] = (wsum[0] + wsum[1]) * (1.0f / 64.0f);
}

// ---------------------------------------------------------------------------
// Kernel 2: block = 64 query rows x 128 classes, 4 waves, grid 1024.
// Stage: wave w converts rows [16w, 16w+16) to A-frag layout in LDS (two
// passes of the 8-row pattern). Then each wave reads all 16 A-frags
// (4mt x 4k) and runs the ping-pong b-loop over its 2 c-tiles: each 8-KB
// B-frag load feeds 4 m-tiles. One barrier total.
// ---------------------------------------------------------------------------
#define SLOT_STRIDE 520   // 512 shorts payload + 8 pad -> slot base moves 4 banks

__global__ __launch_bounds__(256, 2) void dist_kernel(
    const float* __restrict__ q, const uint4* __restrict__ pfrag,
    const float* __restrict__ p2, float* __restrict__ out) {
  int tid  = threadIdx.x;
  int w    = tid >> 6, lane = tid & 63;
  int l15  = lane & 15, quad = lane >> 4;
  int q0   = blockIdx.x << 6;                        // 64 rows per block

  __shared__ unsigned short aflds[16 * SLOT_STRIDE]; // A-frags, slot = mt*4 + i
  __shared__ float q2s[64];                          // |q|^2 per row (unscaled)

  // --- staging: this wave converts rows 16w..16w+15; lane = (row_local, chunk)
  // chunk = 16-float slice of D. A-frag target: slot (mt, i=chunk>>1), within
  // slot position p = quad*16 + m, 8 shorts each; this lane covers quads
  // (chunk&1)*2 and (chunk&1)*2+1 of row m.
  #pragma unroll
  for (int pass = 0; pass < 2; ++pass) {
    int rloc  = w * 16 + pass * 8 + (lane >> 3);     // 0..63 local row
    int chunk = lane & 7;
    const float* src = q + (size_t)(q0 + rloc) * DIM + chunk * 16;
    float4 x0 = *reinterpret_cast<const float4*>(src);
    float4 x1 = *reinterpret_cast<const float4*>(src + 4);
    float4 x2 = *reinterpret_cast<const float4*>(src + 8);
    float4 x3 = *reinterpret_cast<const float4*>(src + 12);
    float s = x0.x*x0.x + x0.y*x0.y + x0.z*x0.z + x0.w*x0.w
            + x1.x*x1.x + x1.y*x1.y + x1.z*x1.z + x1.w*x1.w
            + x2.x*x2.x + x2.y*x2.y + x2.z*x2.z + x2.w*x2.w
            + x3.x*x3.x + x3.y*x3.y + x3.z*x3.z + x3.w*x3.w;
    s += __shfl_down(s, 4, 8);              // reduce over the row's 8 chunks
    s += __shfl_down(s, 2, 8);
    s += __shfl_down(s, 1, 8);
    if (chunk == 0) q2s[rloc] = s;

    int mt = rloc >> 4, m = rloc & 15, i = chunk >> 1, h = chunk & 1;
    unsigned short* base = &aflds[(mt * 4 + i) * SLOT_STRIDE];
    *reinterpret_cast<short8*>(&base[((h * 2 + 0) * 16 + m) * 8]) = pack8_bf16(x0, x1);
    *reinterpret_cast<short8*>(&base[((h * 2 + 1) * 16 + m) * 8]) = pack8_bf16(x2, x3);
  }
  __syncthreads();

  // --- every wave pulls all 16 A-frags + q2' from LDS ---
  short8 af[4][4];
  #pragma unroll
  for (int mt = 0; mt < 4; ++mt)
    #pragma unroll
    for (int k = 0; k < 4; ++k)
      af[mt][k] = *reinterpret_cast<const short8*>(
          &aflds[(mt * 4 + k) * SLOT_STRIDE + lane * 8]);

  f32x4 q2r[4];                    // q2' for C/D row quad*4+r of each m-tile
  #pragma unroll
  for (int mt = 0; mt < 4; ++mt)
    #pragma unroll
    for (int r = 0; r < 4; ++r)
      q2r[mt][r] = q2s[mt * 16 + quad * 4 + r] * (1.0f / 64.0f);

  // p2' hoisted for this wave's two c-tiles, all b (16 L2-hot dwords)
  float p2v[NB][2];
  #pragma unroll
  for (int b = 0; b < NB; ++b)
    #pragma unroll
    for (int jj = 0; jj < 2; ++jj)
      p2v[b][jj] = p2[b * NCLS + (w * 2 + jj) * 16 + l15];

  f32x4 oacc[4][2];
  #pragma unroll
  for (int mt = 0; mt < 4; ++mt)
    #pragma unroll
    for (int jj = 0; jj < 2; ++jj)
      oacc[mt][jj] = (f32x4){0.f, 0.f, 0.f, 0.f};

  // --- b-loop: X/Y ping-pong, 8 frag loads in flight across each compute ---
  uint4 bufX[8], bufY[8];

  #define LOAD_B(BUF, B)                                                      \
    {                                                                         \
      _Pragma("unroll")                                                       \
      for (int jj = 0; jj < 2; ++jj) {                                        \
        int ct = w * 2 + jj;                                                  \
        const uint4* bp = pfrag + (size_t)(((B) * 8 + ct) * 4) * 64 + lane;   \
        _Pragma("unroll")                                                     \
        for (int k = 0; k < 4; ++k) BUF[jj * 4 + k] = bp[k * 64];             \
      }                                                                       \
    }

  #define COMPUTE_B(BUF, B)                                                   \
    {                                                                         \
      _Pragma("unroll")                                                       \
      for (int jj = 0; jj < 2; ++jj) {                                        \
        f32x4 qp[4];                                                          \
        _Pragma("unroll")                                                     \
        for (int mt = 0; mt < 4; ++mt)                                        \
          _Pragma("unroll")                                                   \
          for (int r = 0; r < 4; ++r)                                         \
            qp[mt][r] = q2r[mt][r] + p2v[B][jj];                              \
        __builtin_amdgcn_s_setprio(1);                                        \
        _Pragma("unroll")                                                     \
        for (int k = 0; k < 4; ++k) {                                         \
          short8 bfk = __builtin_bit_cast(short8, BUF[jj * 4 + k]);           \
          _Pragma("unroll")                                                   \
          for (int mt = 0; mt < 4; ++mt)                                      \
            qp[mt] = __builtin_amdgcn_mfma_f32_16x16x32_bf16(af[mt][k], bfk, qp[mt], 0, 0, 0); \
        }                                                                     \
        __builtin_amdgcn_s_setprio(0);                                        \
        _Pragma("unroll")                                                     \
        for (int mt = 0; mt < 4; ++mt)                                        \
          _Pragma("unroll")                                                   \
          for (int r = 0; r < 4; ++r)                                         \
            oacc[mt][jj][r] += fast_sqrt(fmaxf(qp[mt][r], 0.0f));             \
      }                                                                       \
    }

  LOAD_B(bufX, 0)
  #pragma unroll 1
  for (int i = 0; i < NB; i += 2) {
    LOAD_B(bufY, i + 1)                 // in flight across X's compute
    COMPUTE_B(bufX, i)
    LOAD_B(bufX, (i + 2) & (NB - 1))    // wraps to b=0 on last iter (harmless)
    COMPUTE_B(bufY, i + 1)
  }
  #undef LOAD_B
  #undef COMPUTE_B

  // --- store: row = q0 + mt2*16 + quad*4 + r, col = (2w+jj)*16 + l15 ---
  #pragma unroll
  for (int mt2 = 0; mt2 < 4; ++mt2)
    #pragma unroll
    for (int jj = 0; jj < 2; ++jj) {
      int col = (w * 2 + jj) * 16 + l15;
      #pragma unroll
      for (int r = 0; r < 4; ++r) {
        int row = q0 + mt2 * 16 + quad * 4 + r;
        out[(size_t)row * NCLS + col] = -oacc[mt2][jj][r];
      }
    }
}

extern "C" void kernel_launch(void* const* d_in, const int* in_sizes, int n_in,
                              void* d_out, int out_size, void* d_ws, size_t ws_size,
                              hipStream_t stream) {
  const float* sup   = (const float*)d_in[0];   // [4096,128] f32
  // d_in[1] = support_labels (unused: sorted/balanced by construction)
  const float* query = (const float*)d_in[2];   // [65536,128] f32
  const int*   bidx  = (const int*)d_in[3];     // [8,128,32] i32
  float* out = (float*)d_out;                   // [65536,128] f32

  unsigned short* pfrag = (unsigned short*)d_ws;              // 256 KB bf16 frags
  float* p2 = (float*)((char*)d_ws + (size_t)NB * NCLS * DIM * 2); // 4 KB

  proto_kernel<<<NB * NCLS, 128, 0, stream>>>(sup, bidx, pfrag, p2);
  dist_kernel<<<NQ / 64, 256, 0, stream>>>(query, (const uint4*)pfrag, p2, out);
}

// Round 7
// 107.772 us; speedup vs baseline: 1.7958x; 1.0193x over previous
//
#include <hip/hip_runtime.h>
#include <hip/hip_bf16.h>

// PrototypicalNetwork: out[q,c] = -1/8 * sum_b sqrt(max(q2[q] + p2[b,c] - 2*qp[b,q,c], 0))
// bf16 MFMA 16x16x32 for qp GEMM (M=65536, N=1024, K=128).
// R13 = R12 (R7 structure + setprio; measured best 109.9us) with ONE change:
// the hoisted p2v[NB][2] array was RUNTIME-indexed (p2v[B][jj] with loop-var B
// under #pragma unroll 1) -> rule-#20 scratch hazard on the C-init critical
// path, present in R6/R7/R12, never isolated on this structure (R9 fixed it
// but bundled with 32-row blocks). Replaced by per-step scalar ping-pong
// loads ppX/ppY issued one step ahead inside LOAD_B (p2 is a 4KB L2-hot
// table). Named scalars = compile-time regs; -16 arch registers.

#define DIM   128
#define NCLS  128
#define SHOTS 32
#define NB    8
#define NQ    65536

using short8 = __attribute__((ext_vector_type(8))) short;
using f32x4  = __attribute__((ext_vector_type(4))) float;

__device__ __forceinline__ unsigned short f2bf(float x) {
  union { float f; unsigned u; } v; v.f = x;
  unsigned r = v.u + 0x7fffu + ((v.u >> 16) & 1u);   // RNE
  return (unsigned short)(r >> 16);
}

__device__ __forceinline__ short8 pack8_bf16(float4 a, float4 b) {
  // v_cvt_pk_bf16_f32 on gfx950 (RNE), 4 insts for 8 elements
  __hip_bfloat162 p0 = __float22bfloat162_rn(make_float2(a.x, a.y));
  __hip_bfloat162 p1 = __float22bfloat162_rn(make_float2(a.z, a.w));
  __hip_bfloat162 p2 = __float22bfloat162_rn(make_float2(b.x, b.y));
  __hip_bfloat162 p3 = __float22bfloat162_rn(make_float2(b.z, b.w));
  union { __hip_bfloat162 h[4]; short8 s; } u;
  u.h[0] = p0; u.h[1] = p1; u.h[2] = p2; u.h[3] = p3;
  return u.s;
}

__device__ __forceinline__ float fast_sqrt(float x) {
#if __has_builtin(__builtin_amdgcn_sqrtf)
  return __builtin_amdgcn_sqrtf(x);   // raw v_sqrt_f32 (never IEEE sqrtf here — R3 regression)
#else
  return sqrtf(x);
#endif
}

// ---------------------------------------------------------------------------
// Kernel 1: bootstrap-mean protos -> bf16(-proto/32) in MFMA B-frag-major
// layout, plus p2[b,c] = |proto|^2 / 64 (fp32).
// B-frag layout (16x16x32): lane holds B[n=lane&15][k=(lane>>4)*8+j].
// Slot = (b*8+ct)*4+kiter; one slot = 64 lanes * 16 B = 1 KB contiguous.
// ---------------------------------------------------------------------------
__global__ __launch_bounds__(128) void proto_kernel(
    const float* __restrict__ sup, const int* __restrict__ bidx,
    unsigned short* __restrict__ pfrag, float* __restrict__ p2) {
  int bc = blockIdx.x;            // b*128 + c
  int c  = bc & (NCLS - 1);
  int d  = threadIdx.x;           // 0..127 = feature dim
  __shared__ int   sidx[SHOTS];
  __shared__ float wsum[2];
  if (d < SHOTS) sidx[d] = bidx[bc * SHOTS + d];
  __syncthreads();
  float acc = 0.f;
  const float* base = sup + c * SHOTS * DIM + d;
  #pragma unroll
  for (int s = 0; s < SHOTS; ++s) acc += base[sidx[s] * DIM];
  float proto = acc * (1.0f / 32.0f);

  int b     = bc >> 7;
  int ct    = c >> 4, l15c = c & 15;
  int kiter = d >> 5, quad = (d >> 3) & 3, j = d & 7;
  int lane  = l15c + (quad << 4);
  int slot  = (b * 8 + ct) * 4 + kiter;
  pfrag[slot * 512 + lane * 8 + j] = f2bf(proto * -0.03125f);  // -proto/32

  float sq = proto * proto;
  #pragma unroll
  for (int off = 32; off > 0; off >>= 1) sq += __shfl_down(sq, off, 64);
  if ((d & 63) == 0) wsum[d >> 6] = sq;
  __syncthreads();
  if (d == 0) p2[bc] = (wsum[0] + wsum[1]) * (1.0f / 64.0f);
}

// ---------------------------------------------------------------------------
// Kernel 2: block = 64 query rows x 128 classes, 4 waves, grid 1024.
// Stage: wave w converts rows [16w, 16w+16) to A-frag layout in LDS (two
// passes of the 8-row pattern). Then each wave reads all 16 A-frags
// (4mt x 4k) and runs the ping-pong b-loop over its 2 c-tiles: each 8-KB
// B-frag load feeds 4 m-tiles. One barrier total.
// ---------------------------------------------------------------------------
#define SLOT_STRIDE 520   // 512 shorts payload + 8 pad -> slot base moves 4 banks

__global__ __launch_bounds__(256, 2) void dist_kernel(
    const float* __restrict__ q, const uint4* __restrict__ pfrag,
    const float* __restrict__ p2, float* __restrict__ out) {
  int tid  = threadIdx.x;
  int w    = tid >> 6, lane = tid & 63;
  int l15  = lane & 15, quad = lane >> 4;
  int q0   = blockIdx.x << 6;                        // 64 rows per block

  __shared__ unsigned short aflds[16 * SLOT_STRIDE]; // A-frags, slot = mt*4 + i
  __shared__ float q2s[64];                          // |q|^2 per row (unscaled)

  // --- staging: this wave converts rows 16w..16w+15; lane = (row_local, chunk)
  // chunk = 16-float slice of D. A-frag target: slot (mt, i=chunk>>1), within
  // slot position p = quad*16 + m, 8 shorts each; this lane covers quads
  // (chunk&1)*2 and (chunk&1)*2+1 of row m.
  #pragma unroll
  for (int pass = 0; pass < 2; ++pass) {
    int rloc  = w * 16 + pass * 8 + (lane >> 3);     // 0..63 local row
    int chunk = lane & 7;
    const float* src = q + (size_t)(q0 + rloc) * DIM + chunk * 16;
    float4 x0 = *reinterpret_cast<const float4*>(src);
    float4 x1 = *reinterpret_cast<const float4*>(src + 4);
    float4 x2 = *reinterpret_cast<const float4*>(src + 8);
    float4 x3 = *reinterpret_cast<const float4*>(src + 12);
    float s = x0.x*x0.x + x0.y*x0.y + x0.z*x0.z + x0.w*x0.w
            + x1.x*x1.x + x1.y*x1.y + x1.z*x1.z + x1.w*x1.w
            + x2.x*x2.x + x2.y*x2.y + x2.z*x2.z + x2.w*x2.w
            + x3.x*x3.x + x3.y*x3.y + x3.z*x3.z + x3.w*x3.w;
    s += __shfl_down(s, 4, 8);              // reduce over the row's 8 chunks
    s += __shfl_down(s, 2, 8);
    s += __shfl_down(s, 1, 8);
    if (chunk == 0) q2s[rloc] = s;

    int mt = rloc >> 4, m = rloc & 15, i = chunk >> 1, h = chunk & 1;
    unsigned short* base = &aflds[(mt * 4 + i) * SLOT_STRIDE];
    *reinterpret_cast<short8*>(&base[((h * 2 + 0) * 16 + m) * 8]) = pack8_bf16(x0, x1);
    *reinterpret_cast<short8*>(&base[((h * 2 + 1) * 16 + m) * 8]) = pack8_bf16(x2, x3);
  }
  __syncthreads();

  // --- every wave pulls all 16 A-frags + q2' from LDS ---
  short8 af[4][4];
  #pragma unroll
  for (int mt = 0; mt < 4; ++mt)
    #pragma unroll
    for (int k = 0; k < 4; ++k)
      af[mt][k] = *reinterpret_cast<const short8*>(
          &aflds[(mt * 4 + k) * SLOT_STRIDE + lane * 8]);

  f32x4 q2r[4];                    // q2' for C/D row quad*4+r of each m-tile
  #pragma unroll
  for (int mt = 0; mt < 4; ++mt)
    #pragma unroll
    for (int r = 0; r < 4; ++r)
      q2r[mt][r] = q2s[mt * 16 + quad * 4 + r] * (1.0f / 64.0f);

  f32x4 oacc[4][2];
  #pragma unroll
  for (int mt = 0; mt < 4; ++mt)
    #pragma unroll
    for (int jj = 0; jj < 2; ++jj)
      oacc[mt][jj] = (f32x4){0.f, 0.f, 0.f, 0.f};

  // --- b-loop: X/Y ping-pong, 8 frag loads + 2 p2 scalars in flight ---
  uint4 bufX[8], bufY[8];
  float ppX0, ppX1, ppY0, ppY1;    // p2' scalars, named (no runtime indexing)

  #define LOAD_B(BUF, P0, P1, B)                                              \
    {                                                                         \
      _Pragma("unroll")                                                       \
      for (int jj = 0; jj < 2; ++jj) {                                        \
        int ct = w * 2 + jj;                                                  \
        const uint4* bp = pfrag + (size_t)(((B) * 8 + ct) * 4) * 64 + lane;   \
        _Pragma("unroll")                                                     \
        for (int k = 0; k < 4; ++k) BUF[jj * 4 + k] = bp[k * 64];             \
      }                                                                       \
      P0 = p2[(B) * NCLS + (w * 2 + 0) * 16 + l15];                           \
      P1 = p2[(B) * NCLS + (w * 2 + 1) * 16 + l15];                           \
    }

  #define COMPUTE_B(BUF, P0, P1)                                              \
    {                                                                         \
      _Pragma("unroll")                                                       \
      for (int jj = 0; jj < 2; ++jj) {                                        \
        float pp = (jj == 0) ? P0 : P1;                                       \
        f32x4 qp[4];                                                          \
        _Pragma("unroll")                                                     \
        for (int mt = 0; mt < 4; ++mt)                                        \
          _Pragma("unroll")                                                   \
          for (int r = 0; r < 4; ++r)                                         \
            qp[mt][r] = q2r[mt][r] + pp;                                      \
        __builtin_amdgcn_s_setprio(1);                                        \
        _Pragma("unroll")                                                     \
        for (int k = 0; k < 4; ++k) {                                         \
          short8 bfk = __builtin_bit_cast(short8, BUF[jj * 4 + k]);           \
          _Pragma("unroll")                                                   \
          for (int mt = 0; mt < 4; ++mt)                                      \
            qp[mt] = __builtin_amdgcn_mfma_f32_16x16x32_bf16(af[mt][k], bfk, qp[mt], 0, 0, 0); \
        }                                                                     \
        __builtin_amdgcn_s_setprio(0);                                        \
        _Pragma("unroll")                                                     \
        for (int mt = 0; mt < 4; ++mt)                                        \
          _Pragma("unroll")                                                   \
          for (int r = 0; r < 4; ++r)                                         \
            oacc[mt][jj][r] += fast_sqrt(fmaxf(qp[mt][r], 0.0f));             \
      }                                                                       \
    }

  LOAD_B(bufX, ppX0, ppX1, 0)
  #pragma unroll 1
  for (int i = 0; i < NB; i += 2) {
    LOAD_B(bufY, ppY0, ppY1, i + 1)               // in flight across X's compute
    COMPUTE_B(bufX, ppX0, ppX1)
    LOAD_B(bufX, ppX0, ppX1, (i + 2) & (NB - 1))  // wraps to b=0 on last iter
    COMPUTE_B(bufY, ppY0, ppY1)
  }
  #undef LOAD_B
  #undef COMPUTE_B

  // --- store: row = q0 + mt2*16 + quad*4 + r, col = (2w+jj)*16 + l15 ---
  #pragma unroll
  for (int mt2 = 0; mt2 < 4; ++mt2)
    #pragma unroll
    for (int jj = 0; jj < 2; ++jj) {
      int col = (w * 2 + jj) * 16 + l15;
      #pragma unroll
      for (int r = 0; r < 4; ++r) {
        int row = q0 + mt2 * 16 + quad * 4 + r;
        out[(size_t)row * NCLS + col] = -oacc[mt2][jj][r];
      }
    }
}

extern "C" void kernel_launch(void* const* d_in, const int* in_sizes, int n_in,
                              void* d_out, int out_size, void* d_ws, size_t ws_size,
                              hipStream_t stream) {
  const float* sup   = (const float*)d_in[0];   // [4096,128] f32
  // d_in[1] = support_labels (unused: sorted/balanced by construction)
  const float* query = (const float*)d_in[2];   // [65536,128] f32
  const int*   bidx  = (const int*)d_in[3];     // [8,128,32] i32
  float* out = (float*)d_out;                   // [65536,128] f32

  unsigned short* pfrag = (unsigned short*)d_ws;              // 256 KB bf16 frags
  float* p2 = (float*)((char*)d_ws + (size_t)NB * NCLS * DIM * 2); // 4 KB

  proto_kernel<<<NB * NCLS, 128, 0, stream>>>(sup, bidx, pfrag, p2);
  dist_kernel<<<NQ / 64, 256, 0, stream>>>(query, (const uint4*)pfrag, p2, out);
}